// Round 5
// baseline (104.762 us; speedup 1.0000x reference)
//
#include <hip/hip_runtime.h>
#include <hip/hip_bf16.h>

typedef __bf16 bf8 __attribute__((ext_vector_type(8)));
typedef float f32x4 __attribute__((ext_vector_type(4)));
typedef unsigned short u16x4 __attribute__((ext_vector_type(4)));

#define NBINS 129
#define ROWS_IT 32               // rows per iteration
#define ITERS 8                  // iterations per block (256 rows/block)
#define KSTR 136                 // LDS k-stride (elems); 272B rows
#define MATOFF (ROWS_IT * KSTR)  // elems per matrix per buffer
#define BUFE (2 * MATOFF)        // elems per buffer (17408 B)

__device__ __forceinline__ unsigned short f2bf(float x) {
    return __builtin_bit_cast(unsigned short, (__bf16)x);
}

__device__ __forceinline__ void issue_loads(const float* __restrict__ re,
                                            const float* __restrict__ im,
                                            int rowbase, int myrow, int mycol, int tid,
                                            f32x4* v, float* tl)
{
    #pragma unroll
    for (int m = 0; m < 2; ++m) {
        const float* srcp = m ? im : re;
        #pragma unroll
        for (int jj = 0; jj < 4; ++jj)
            __builtin_memcpy(&v[m * 4 + jj],
                             srcp + (rowbase + myrow + jj * 8) * NBINS + mycol * 4, 16);
    }
    float t = 0.0f;
    if (tid < 64) {
        const float* srcp = (tid < 32) ? re : im;
        t = srcp[(rowbase + (tid & 31)) * NBINS + 128];
    }
    *tl = t;
}

__global__ __launch_bounds__(256, 4)
void irfft_mm(const float* __restrict__ re,
              const float* __restrict__ im,
              const float* __restrict__ mr,
              const float* __restrict__ mi,
              float* __restrict__ out)
{
    __shared__ unsigned short lds[2][BUFE];   // 34816 B -> 4 blocks/CU

    const int tid   = threadIdx.x;
    const int lane  = tid & 63;
    const int w     = tid >> 6;   // wave id = 16-col block of output
    const int r16   = lane & 15;
    const int q     = lane >> 4;
    const int myrow = tid >> 5;   // 0..7 (staging row-group)
    const int mycol = tid & 31;   // staging 16B-chunk index

    const int blockrow = blockIdx.x * (ROWS_IT * ITERS);

    // ---- 2-deep prefetch: issue batches for it=0 and it=1 ----
    f32x4 v[2][8];
    float tl[2];
    issue_loads(re, im, blockrow,           myrow, mycol, tid, v[0], &tl[0]);
    issue_loads(re, im, blockrow + ROWS_IT, myrow, mycol, tid, v[1], &tl[1]);

    // ---- A fragments (M^T) from global into registers; L2/L3-hot ----
    bf8 afr[2][4];
    #pragma unroll
    for (int m = 0; m < 2; ++m) {
        const float* M = m ? mi : mr;
        #pragma unroll
        for (int t = 0; t < 4; ++t) {
            bf8 a;
            #pragma unroll
            for (int j = 0; j < 8; ++j)
                a[j] = (__bf16)M[(t * 32 + q * 8 + j) * 64 + w * 16 + r16];
            afr[m][t] = a;
        }
    }
    const f32x4 mt0 = *(const f32x4*)(mr + 128 * 64 + w * 16 + q * 4);
    const f32x4 mt1 = *(const f32x4*)(mi + 128 * 64 + w * 16 + q * 4);

    #pragma unroll
    for (int it = 0; it < ITERS; ++it) {
        unsigned short* buf = lds[it & 1];
        const int rowbase = blockrow + it * ROWS_IT;
        f32x4* vc = v[it & 1];

        // ---- convert + stage batch L(it) (issued 2 iterations ago) ----
        #pragma unroll
        for (int m = 0; m < 2; ++m)
            #pragma unroll
            for (int jj = 0; jj < 4; ++jj) {
                const f32x4 x = vc[m * 4 + jj];
                u16x4 h;
                h[0] = f2bf(x[0]); h[1] = f2bf(x[1]);
                h[2] = f2bf(x[2]); h[3] = f2bf(x[3]);
                *(u16x4*)&buf[m * MATOFF + (myrow + jj * 8) * KSTR + mycol * 4] = h;
            }
        if (tid < 64)
            buf[(tid >> 5) * MATOFF + (tid & 31) * KSTR + 128] = f2bf(tl[it & 1]);

        // ---- re-issue the freed registers as batch L(it+2) ----
        if (it + 2 < ITERS)
            issue_loads(re, im, rowbase + 2 * ROWS_IT, myrow, mycol, tid,
                        vc, &tl[it & 1]);

        // LDS writes visible; vmcnt NOT drained (both prefetch batches in flight)
        asm volatile("s_waitcnt lgkmcnt(0)" ::: "memory");
        __builtin_amdgcn_s_barrier();
        asm volatile("" ::: "memory");

        // ---- compute 32 rows x 16 cols per wave ----
        f32x4 acc0 = {0.0f, 0.0f, 0.0f, 0.0f};
        f32x4 acc1 = {0.0f, 0.0f, 0.0f, 0.0f};

        #pragma unroll
        for (int m = 0; m < 2; ++m) {
            #pragma unroll
            for (int t = 0; t < 4; ++t) {
                bf8 b0 = *(const bf8*)&buf[m * MATOFF + r16 * KSTR + t * 32 + q * 8];
                bf8 b1 = *(const bf8*)&buf[m * MATOFF + (16 + r16) * KSTR + t * 32 + q * 8];
                acc0 = __builtin_amdgcn_mfma_f32_16x16x32_bf16(afr[m][t], b0, acc0, 0, 0, 0);
                acc1 = __builtin_amdgcn_mfma_f32_16x16x32_bf16(afr[m][t], b1, acc1, 0, 0, 0);
            }
            // k = 128 rank-1 tail in f32 VALU
            const f32x4 mt = m ? mt1 : mt0;
            const float x0 =
                (float)__builtin_bit_cast(__bf16, buf[m * MATOFF + r16 * KSTR + 128]);
            const float x1 =
                (float)__builtin_bit_cast(__bf16, buf[m * MATOFF + (16 + r16) * KSTR + 128]);
            #pragma unroll
            for (int jj = 0; jj < 4; ++jj) {
                acc0[jj] += x0 * mt[jj];
                acc1[jj] += x1 * mt[jj];
            }
        }

        // ---- coalesced non-temporal f32x4 stores ----
        __builtin_nontemporal_store(
            acc0, (f32x4*)(out + (rowbase + r16) * 64 + w * 16 + q * 4));
        __builtin_nontemporal_store(
            acc1, (f32x4*)(out + (rowbase + 16 + r16) * 64 + w * 16 + q * 4));
    }
}

extern "C" void kernel_launch(void* const* d_in, const int* in_sizes, int n_in,
                              void* d_out, int out_size, void* d_ws, size_t ws_size,
                              hipStream_t stream)
{
    const float* re = (const float*)d_in[0];
    const float* im = (const float*)d_in[1];
    const float* mr = (const float*)d_in[2];
    const float* mi = (const float*)d_in[3];
    float* out = (float*)d_out;

    const long rows = (long)in_sizes[0] / NBINS;          // 256000
    const int grid = (int)(rows / (ROWS_IT * ITERS));     // 1000 (exact)
    irfft_mm<<<grid, 256, 0, stream>>>(re, im, mr, mi, out);
}

// Round 6
// 88.867 us; speedup vs baseline: 1.1789x; 1.1789x over previous
//
#include <hip/hip_runtime.h>
#include <hip/hip_bf16.h>

typedef __bf16 bf8 __attribute__((ext_vector_type(8)));
typedef float f32x4 __attribute__((ext_vector_type(4)));
typedef unsigned short u16x4 __attribute__((ext_vector_type(4)));

#define NBINS 129
#define ROWS_IT 32               // rows per iteration
#define ITERS 8                  // iterations per block (256 rows/block)
#define KSTR 136                 // LDS k-stride (elems); 272B rows
#define MATOFF (ROWS_IT * KSTR)  // elems per matrix per buffer
#define BUFE (2 * MATOFF)        // elems per buffer (17408 B)

__device__ __forceinline__ unsigned short f2bf(float x) {
    return __builtin_bit_cast(unsigned short, (__bf16)x);
}

__device__ __forceinline__ void issue_loads(const float* __restrict__ re,
                                            const float* __restrict__ im,
                                            int rowbase, int myrow, int mycol, int tid,
                                            f32x4* v, float* tl)
{
    #pragma unroll
    for (int m = 0; m < 2; ++m) {
        const float* srcp = m ? im : re;
        #pragma unroll
        for (int jj = 0; jj < 4; ++jj)
            __builtin_memcpy(&v[m * 4 + jj],
                             srcp + (rowbase + myrow + jj * 8) * NBINS + mycol * 4, 16);
    }
    float t = 0.0f;
    if (tid < 64) {
        const float* srcp = (tid < 32) ? re : im;
        t = srcp[(rowbase + (tid & 31)) * NBINS + 128];
    }
    *tl = t;
}

__global__ __launch_bounds__(256, 3)
void irfft_mm(const float* __restrict__ re,
              const float* __restrict__ im,
              const float* __restrict__ mr,
              const float* __restrict__ mi,
              float* __restrict__ out)
{
    __shared__ unsigned short lds[2][BUFE];   // 34816 B

    const int tid   = threadIdx.x;
    const int lane  = tid & 63;
    const int w     = tid >> 6;   // wave id = 16-col block of output
    const int r16   = lane & 15;
    const int q     = lane >> 4;
    const int myrow = tid >> 5;   // 0..7 (staging row-group)
    const int mycol = tid & 31;   // staging 16B-chunk index

    const int blockrow = blockIdx.x * (ROWS_IT * ITERS);

    // ---- 2-deep prefetch: issue batches for it=0 and it=1 ----
    f32x4 v[2][8];
    float tl[2];
    issue_loads(re, im, blockrow,           myrow, mycol, tid, v[0], &tl[0]);
    issue_loads(re, im, blockrow + ROWS_IT, myrow, mycol, tid, v[1], &tl[1]);

    // ---- A fragments (M^T) from global into registers; L2/L3-hot ----
    bf8 afr[2][4];
    #pragma unroll
    for (int m = 0; m < 2; ++m) {
        const float* M = m ? mi : mr;
        #pragma unroll
        for (int t = 0; t < 4; ++t) {
            bf8 a;
            #pragma unroll
            for (int j = 0; j < 8; ++j)
                a[j] = (__bf16)M[(t * 32 + q * 8 + j) * 64 + w * 16 + r16];
            afr[m][t] = a;
        }
    }
    const f32x4 mt0 = *(const f32x4*)(mr + 128 * 64 + w * 16 + q * 4);
    const f32x4 mt1 = *(const f32x4*)(mi + 128 * 64 + w * 16 + q * 4);

    #pragma unroll
    for (int it = 0; it < ITERS; ++it) {
        unsigned short* buf = lds[it & 1];
        const int rowbase = blockrow + it * ROWS_IT;
        f32x4* vc = v[it & 1];

        // ---- convert + stage batch L(it) (issued 2 iterations ago) ----
        #pragma unroll
        for (int m = 0; m < 2; ++m)
            #pragma unroll
            for (int jj = 0; jj < 4; ++jj) {
                const f32x4 x = vc[m * 4 + jj];
                u16x4 h;
                h[0] = f2bf(x[0]); h[1] = f2bf(x[1]);
                h[2] = f2bf(x[2]); h[3] = f2bf(x[3]);
                *(u16x4*)&buf[m * MATOFF + (myrow + jj * 8) * KSTR + mycol * 4] = h;
            }
        if (tid < 64)
            buf[(tid >> 5) * MATOFF + (tid & 31) * KSTR + 128] = f2bf(tl[it & 1]);

        // ---- re-issue the freed registers as batch L(it+2) ----
        if (it + 2 < ITERS)
            issue_loads(re, im, rowbase + 2 * ROWS_IT, myrow, mycol, tid,
                        vc, &tl[it & 1]);

        // LDS writes visible; vmcnt NOT drained (both prefetch batches in flight)
        asm volatile("s_waitcnt lgkmcnt(0)" ::: "memory");
        __builtin_amdgcn_s_barrier();
        asm volatile("" ::: "memory");

        // ---- compute 32 rows x 16 cols per wave ----
        f32x4 acc0 = {0.0f, 0.0f, 0.0f, 0.0f};
        f32x4 acc1 = {0.0f, 0.0f, 0.0f, 0.0f};

        #pragma unroll
        for (int m = 0; m < 2; ++m) {
            #pragma unroll
            for (int t = 0; t < 4; ++t) {
                bf8 b0 = *(const bf8*)&buf[m * MATOFF + r16 * KSTR + t * 32 + q * 8];
                bf8 b1 = *(const bf8*)&buf[m * MATOFF + (16 + r16) * KSTR + t * 32 + q * 8];
                acc0 = __builtin_amdgcn_mfma_f32_16x16x32_bf16(afr[m][t], b0, acc0, 0, 0, 0);
                acc1 = __builtin_amdgcn_mfma_f32_16x16x32_bf16(afr[m][t], b1, acc1, 0, 0, 0);
            }
            // k = 128 rank-1 tail in f32 VALU
            const f32x4 mt = m ? mt1 : mt0;
            const float x0 =
                (float)__builtin_bit_cast(__bf16, buf[m * MATOFF + r16 * KSTR + 128]);
            const float x1 =
                (float)__builtin_bit_cast(__bf16, buf[m * MATOFF + (16 + r16) * KSTR + 128]);
            #pragma unroll
            for (int jj = 0; jj < 4; ++jj) {
                acc0[jj] += x0 * mt[jj];
                acc1[jj] += x1 * mt[jj];
            }
        }

        // ---- coalesced f32x4 stores (L2-merged full lines across the 4 waves) ----
        *(f32x4*)(out + (rowbase + r16) * 64 + w * 16 + q * 4) = acc0;
        *(f32x4*)(out + (rowbase + 16 + r16) * 64 + w * 16 + q * 4) = acc1;
    }
}

extern "C" void kernel_launch(void* const* d_in, const int* in_sizes, int n_in,
                              void* d_out, int out_size, void* d_ws, size_t ws_size,
                              hipStream_t stream)
{
    const float* re = (const float*)d_in[0];
    const float* im = (const float*)d_in[1];
    const float* mr = (const float*)d_in[2];
    const float* mi = (const float*)d_in[3];
    float* out = (float*)d_out;

    const long rows = (long)in_sizes[0] / NBINS;          // 256000
    const int grid = (int)(rows / (ROWS_IT * ITERS));     // 1000 (exact)
    irfft_mm<<<grid, 256, 0, stream>>>(re, im, mr, mi, out);
}

// Round 7
// 84.046 us; speedup vs baseline: 1.2465x; 1.0574x over previous
//
#include <hip/hip_runtime.h>
#include <hip/hip_bf16.h>

typedef __bf16 bf8 __attribute__((ext_vector_type(8)));
typedef float f32x4 __attribute__((ext_vector_type(4)));
typedef unsigned short u16x4 __attribute__((ext_vector_type(4)));

#define NBINS 129
#define ROWS_IT 32               // rows per iteration
#define ITERS 8                  // iterations per block (256 rows/block)
#define KSTR 136                 // LDS k-stride (elems); 272B rows (17x16B -> aligned)
#define MATOFF (ROWS_IT * KSTR)  // elems per matrix per buffer
#define BUFE (2 * MATOFF)        // elems per buffer (17408 B)

__device__ __forceinline__ unsigned short f2bf(float x) {
    return __builtin_bit_cast(unsigned short, (__bf16)x);
}

// 512 threads: threads 0-255 stage `re`, 256-511 stage `im`; 4 chunks each.
__device__ __forceinline__ void issue_loads(const float* __restrict__ re,
                                            const float* __restrict__ im,
                                            int rowbase, int myrow, int mycol, int tid,
                                            f32x4* v, float* tl)
{
    const float* srcp = (tid < 256) ? re : im;
    #pragma unroll
    for (int jj = 0; jj < 4; ++jj)
        __builtin_memcpy(&v[jj],
                         srcp + (rowbase + myrow + jj * 8) * NBINS + mycol * 4, 16);
    float t = 0.0f;
    if (tid < 64) {
        const float* sp = (tid < 32) ? re : im;
        t = sp[(rowbase + (tid & 31)) * NBINS + 128];
    }
    *tl = t;
}

__global__ __launch_bounds__(512, 4)
void irfft_mm(const float* __restrict__ re,
              const float* __restrict__ im,
              const float* __restrict__ mr,
              const float* __restrict__ mi,
              float* __restrict__ out)
{
    __shared__ unsigned short lds[2][BUFE];   // 34816 B -> 2 blocks/CU (LDS-light)

    const int tid   = threadIdx.x;
    const int lane  = tid & 63;
    const int w     = tid >> 6;        // wave 0..7
    const int cb    = w & 3;           // col-block (16 cols)
    const int rh    = w >> 2;          // row-half (16 rows)
    const int r16   = lane & 15;
    const int q     = lane >> 4;
    const int myrow = (tid & 255) >> 5;  // 0..7 staging row-group
    const int mycol = tid & 31;          // staging 16B-chunk
    const int mat   = tid >> 8;          // 0: re, 1: im

    const int blockrow = blockIdx.x * (ROWS_IT * ITERS);

    // ---- 2-deep prefetch: batches for it=0 and it=1 ----
    f32x4 v[2][4];
    float tl[2];
    issue_loads(re, im, blockrow,           myrow, mycol, tid, v[0], &tl[0]);
    issue_loads(re, im, blockrow + ROWS_IT, myrow, mycol, tid, v[1], &tl[1]);

    // ---- A fragments (M^T) for this wave's 16-col block; L2/L3-hot ----
    bf8 afr[2][4];
    #pragma unroll
    for (int m = 0; m < 2; ++m) {
        const float* M = m ? mi : mr;
        #pragma unroll
        for (int t = 0; t < 4; ++t) {
            bf8 a;
            #pragma unroll
            for (int j = 0; j < 8; ++j)
                a[j] = (__bf16)M[(t * 32 + q * 8 + j) * 64 + cb * 16 + r16];
            afr[m][t] = a;
        }
    }
    const f32x4 mt0 = *(const f32x4*)(mr + 128 * 64 + cb * 16 + q * 4);
    const f32x4 mt1 = *(const f32x4*)(mi + 128 * 64 + cb * 16 + q * 4);

    #pragma unroll
    for (int it = 0; it < ITERS; ++it) {
        unsigned short* buf = lds[it & 1];
        const int rowbase = blockrow + it * ROWS_IT;
        f32x4* vc = v[it & 1];

        // ---- re-issue freed registers as batch L(it+2) first (max overlap) ----
        f32x4 vnext[4];
        float tlnext = 0.0f;
        if (it + 2 < ITERS)
            issue_loads(re, im, rowbase + 2 * ROWS_IT, myrow, mycol, tid,
                        vnext, &tlnext);

        // ---- convert + stage batch L(it) (issued 2 iterations ago) ----
        #pragma unroll
        for (int jj = 0; jj < 4; ++jj) {
            const f32x4 x = vc[jj];
            u16x4 h;
            h[0] = f2bf(x[0]); h[1] = f2bf(x[1]);
            h[2] = f2bf(x[2]); h[3] = f2bf(x[3]);
            *(u16x4*)&buf[mat * MATOFF + (myrow + jj * 8) * KSTR + mycol * 4] = h;
        }
        if (tid < 64)
            buf[(tid >> 5) * MATOFF + (tid & 31) * KSTR + 128] = f2bf(tl[it & 1]);

        // move vnext into the persistent slot (register rename, no memory)
        #pragma unroll
        for (int jj = 0; jj < 4; ++jj) vc[jj] = vnext[jj];
        tl[it & 1] = tlnext;

        // LDS writes visible; vmcnt NOT drained (prefetch batches stay in flight)
        asm volatile("s_waitcnt lgkmcnt(0)" ::: "memory");
        __builtin_amdgcn_s_barrier();
        asm volatile("" ::: "memory");

        // ---- compute: 16 rows (rh) x 16 cols (cb) per wave ----
        f32x4 acc = {0.0f, 0.0f, 0.0f, 0.0f};
        #pragma unroll
        for (int m = 0; m < 2; ++m) {
            #pragma unroll
            for (int t = 0; t < 4; ++t) {
                bf8 b = *(const bf8*)&buf[m * MATOFF + (rh * 16 + r16) * KSTR
                                          + t * 32 + q * 8];
                acc = __builtin_amdgcn_mfma_f32_16x16x32_bf16(afr[m][t], b, acc, 0, 0, 0);
            }
            const f32x4 mt = m ? mt1 : mt0;
            const float x0 = (float)__builtin_bit_cast(
                __bf16, buf[m * MATOFF + (rh * 16 + r16) * KSTR + 128]);
            #pragma unroll
            for (int jj = 0; jj < 4; ++jj) acc[jj] += x0 * mt[jj];
        }

        // ---- coalesced f32x4 store ----
        *(f32x4*)(out + (rowbase + rh * 16 + r16) * 64 + cb * 16 + q * 4) = acc;
    }
}

extern "C" void kernel_launch(void* const* d_in, const int* in_sizes, int n_in,
                              void* d_out, int out_size, void* d_ws, size_t ws_size,
                              hipStream_t stream)
{
    const float* re = (const float*)d_in[0];
    const float* im = (const float*)d_in[1];
    const float* mr = (const float*)d_in[2];
    const float* mi = (const float*)d_in[3];
    float* out = (float*)d_out;

    const long rows = (long)in_sizes[0] / NBINS;          // 256000
    const int grid = (int)(rows / (ROWS_IT * ITERS));     // 1000 (exact)
    irfft_mm<<<grid, 512, 0, stream>>>(re, im, mr, mi, out);
}

// Round 8
// 69.591 us; speedup vs baseline: 1.5054x; 1.2077x over previous
//
#include <hip/hip_runtime.h>
#include <hip/hip_bf16.h>

typedef __bf16 bf8 __attribute__((ext_vector_type(8)));
typedef float f32x4 __attribute__((ext_vector_type(4)));

#define NBINS 129
#define ROWS_IT 16               // rows per iteration
#define ITERS 16                 // iterations per block (256 rows)
#define MATB 8192                // bytes per mat per buffer (16 rows * 512B)
#define BUFB (2 * MATB)          // 16 KB per buffer

__device__ __forceinline__ void gload_lds16(const float* src, char* ldsdst) {
    __builtin_amdgcn_global_load_lds(
        (const __attribute__((address_space(1))) void*)src,
        (__attribute__((address_space(3))) void*)ldsdst, 16, 0, 0);
}

__global__ __launch_bounds__(256, 4)
void irfft_mm(const float* __restrict__ re,
              const float* __restrict__ im,
              const float* __restrict__ mr,
              const float* __restrict__ mi,
              float* __restrict__ out)
{
    __shared__ __align__(16) char lds[2][BUFB];   // 32 KB -> 4 blocks/CU

    const int tid  = threadIdx.x;
    const int lane = tid & 63;
    const int w    = tid >> 6;   // wave id = output col-block (16 cols)
    const int r16  = lane & 15;
    const int q    = lane >> 4;
    const int rk   = r16 & 7;

    const int blockrow = blockIdx.x * (ROWS_IT * ITERS);

    // staging geometry: wave w stages mat (w>>1), tile rows (w&1)*8 .. +7
    const int    smat  = w >> 1;
    const int    srow0 = (w & 1) * 8;
    const float* ssrc  = smat ? im : re;
    const int    lrow  = lane >> 5;   // 0/1: which of the 2 rows per instr
    const int    p     = lane & 31;   // linear 16B-chunk within row

    float trr[2], tri[2];             // k=128 tails (f32), double-buffered

    // ---- prologue: stage batch 0 + its tails ----
    {
        char* b0 = lds[0];
        #pragma unroll
        for (int i = 0; i < 4; ++i) {
            const int trow = srow0 + 2 * i + lrow;
            const int g    = p ^ (trow & 7);          // pre-swizzled global chunk
            gload_lds16(ssrc + (long)(blockrow + trow) * NBINS + g * 4,
                        b0 + smat * MATB + (srow0 + 2 * i) * 512 + lane * 16);
        }
        trr[0] = re[(long)(blockrow + r16) * NBINS + 128];
        tri[0] = im[(long)(blockrow + r16) * NBINS + 128];
    }

    // ---- A fragments (M^T cols w*16..+15) + f32 tail coefficients ----
    bf8 afr[2][4];
    #pragma unroll
    for (int m = 0; m < 2; ++m) {
        const float* M = m ? mi : mr;
        #pragma unroll
        for (int t = 0; t < 4; ++t) {
            bf8 a;
            #pragma unroll
            for (int j = 0; j < 8; ++j)
                a[j] = (__bf16)M[(t * 32 + q * 8 + j) * 64 + w * 16 + r16];
            afr[m][t] = a;
        }
    }
    const f32x4 mt0 = *(const f32x4*)(mr + 128 * 64 + w * 16 + q * 4);
    const f32x4 mt1 = *(const f32x4*)(mi + 128 * 64 + w * 16 + q * 4);

    #pragma unroll
    for (int it = 0; it < ITERS; ++it) {
        char* bufc = lds[it & 1];
        const int rowbase = blockrow + it * ROWS_IT;

        // ---- issue batch(it+1) into the other buffer ----
        if (it + 1 < ITERS) {
            char* bn = lds[(it + 1) & 1];
            const int rbn = rowbase + ROWS_IT;
            #pragma unroll
            for (int i = 0; i < 4; ++i) {
                const int trow = srow0 + 2 * i + lrow;
                const int g    = p ^ (trow & 7);
                gload_lds16(ssrc + (long)(rbn + trow) * NBINS + g * 4,
                            bn + smat * MATB + (srow0 + 2 * i) * 512 + lane * 16);
            }
            trr[(it + 1) & 1] = re[(long)(rbn + r16) * NBINS + 128];
            tri[(it + 1) & 1] = im[(long)(rbn + r16) * NBINS + 128];
        }

        // ---- counted wait: batch(it) landed; batch(it+1) stays in flight ----
        __builtin_amdgcn_sched_barrier(0);
        if (it + 1 < ITERS) asm volatile("s_waitcnt vmcnt(6)" ::: "memory");
        else                asm volatile("s_waitcnt vmcnt(1)" ::: "memory");
        __builtin_amdgcn_s_barrier();
        __builtin_amdgcn_sched_barrier(0);

        // ---- compute: 16 rows x 16 cols per wave ----
        f32x4 acc = {0.0f, 0.0f, 0.0f, 0.0f};
        #pragma unroll
        for (int m = 0; m < 2; ++m) {
            const char* mb = bufc + m * MATB + r16 * 512;
            #pragma unroll
            for (int t = 0; t < 4; ++t) {
                const int j0 = t * 8 + q * 2;
                const f32x4 lo = *(const f32x4*)(mb + ((j0)     ^ rk) * 16);
                const f32x4 hi = *(const f32x4*)(mb + ((j0 + 1) ^ rk) * 16);
                bf8 bfr;
                #pragma unroll
                for (int jj = 0; jj < 4; ++jj) {
                    bfr[jj]     = (__bf16)lo[jj];
                    bfr[4 + jj] = (__bf16)hi[jj];
                }
                acc = __builtin_amdgcn_mfma_f32_16x16x32_bf16(afr[m][t], bfr, acc, 0, 0, 0);
            }
            // k = 128 rank-1 tail in exact f32
            const float xt = m ? tri[it & 1] : trr[it & 1];
            const f32x4 mt = m ? mt1 : mt0;
            #pragma unroll
            for (int jj = 0; jj < 4; ++jj) acc[jj] += xt * mt[jj];
        }

        // ---- coalesced f32x4 store ----
        *(f32x4*)(out + (long)(rowbase + r16) * 64 + w * 16 + q * 4) = acc;

        // ---- barrier 2: protect buf[it] from stage(it+2) next iteration ----
        if (it + 1 < ITERS) {
            __builtin_amdgcn_sched_barrier(0);
            __builtin_amdgcn_s_barrier();
        }
    }
}

extern "C" void kernel_launch(void* const* d_in, const int* in_sizes, int n_in,
                              void* d_out, int out_size, void* d_ws, size_t ws_size,
                              hipStream_t stream)
{
    const float* re = (const float*)d_in[0];
    const float* im = (const float*)d_in[1];
    const float* mr = (const float*)d_in[2];
    const float* mi = (const float*)d_in[3];
    float* out = (float*)d_out;

    const long rows = (long)in_sizes[0] / NBINS;          // 256000
    const int grid = (int)(rows / (ROWS_IT * ITERS));     // 1000 (exact)
    irfft_mm<<<grid, 256, 0, stream>>>(re, im, mr, mi, out);
}